// Round 8
// baseline (265.061 us; speedup 1.0000x reference)
//
#include <hip/hip_runtime.h>
#include <cstdint>
#include <math.h>

#define B_ 64
#define S_ 512
#define H_ 1024
#define T_ 24
#define TP_ 32     // W padded to 32 rows (zeros) so B-fragment loads never go OOB
#define NC_ 32     // chunks per batch (parallel-scan)
#define CL_ 16     // chunk length in steps
#define KST_ 1040  // floats per (batch,chunk) record: 32x32 K row-major + Ls + pad

typedef unsigned int u32;
typedef unsigned short u16;
typedef __attribute__((ext_vector_type(8))) short short8v;  // 8 bf16 = 4 VGPRs
typedef __attribute__((ext_vector_type(4))) float f32x4;
typedef __attribute__((ext_vector_type(4))) u32 uint4v;

// readlane: value from lane `sl` (wave-uniform index ok), bitcast through uint
__device__ __forceinline__ float rl_f32(float x, int sl) {
    return __uint_as_float(__builtin_amdgcn_readlane(__float_as_uint(x), sl));
}

// Exact-ish two-term split: f = hi + lo (both bf16 by truncation).
// Packs two elements' hi (lo) into one u32, low element in low half.
__device__ __forceinline__ void split_pk(float f0, float f1, u32& hpk, u32& lpk) {
    const u32 u0 = __float_as_uint(f0), u1 = __float_as_uint(f1);
    const u32 t1 = u1 & 0xffff0000u;
    hpk = (u0 >> 16) | t1;
    const float fl0 = f0 - __uint_as_float(u0 & 0xffff0000u);
    const float fl1 = f1 - __uint_as_float(t1);
    lpk = (__float_as_uint(fl0) >> 16) | (__float_as_uint(fl1) & 0xffff0000u);
}

// ---------------------------------------------------------------------------
// Kernel 0: one-shot W split fp32 -> bf16 hi/lo (RTNE), padded to 32 rows.
// Also zeroes the loss accumulator out[0] (re-zeroed every graph replay).
// ---------------------------------------------------------------------------
__global__ __launch_bounds__(256) void wcvt_kernel(const float* __restrict__ W,
                                                   u16* __restrict__ Wh,
                                                   u16* __restrict__ Wl,
                                                   float* __restrict__ out) {
    const int i = blockIdx.x * 256 + threadIdx.x;       // 0 .. 32*1024-1
    if (i == 0) out[0] = 0.f;
    const int t = i >> 10;
    const float f = (t < T_) ? W[i] : 0.f;              // W is [24][1024]; i = t*1024+k
    const u32 u = __float_as_uint(f);
    const u32 rh = u + 0x7fffu + ((u >> 16) & 1u);      // RTNE
    const u16 hb = (u16)(rh >> 16);
    const float fh = __uint_as_float((u32)hb << 16);
    const float fl = f - fh;
    const u32 u2 = __float_as_uint(fl);
    const u32 rl2 = u2 + 0x7fffu + ((u2 >> 16) & 1u);
    Wh[i] = hb;
    Wl[i] = (u16)(rl2 >> 16);
}

// ---------------------------------------------------------------------------
// Kernel 1 (R8): emission GEMM via MFMA, A staged through LDS for coalescing.
// Old version: each A-load instruction touched 16 rows x 2 sectors (~32 L1
// transactions / KB). Now each wave stages its 16-row x 64-float A-chunk with
// lane-contiguous float4 loads (4 x 256B segments per instr), ds_writes into
// a padded float2 [16][33] tile (264B row stride -> ~2-way banks), and reads
// aligned float2 quads back as fragments. Values reaching MFMA are
// bit-identical to the previous kernel. 2 register sets give global loads a
// 2-chunk lead; single per-wave LDS buffer, no barriers (in-order DS pipe).
// Verified conventions for mfma_f32_16x16x32_bf16 (by this kernel passing):
//   A[m][k]: m=lane&15, k=(lane>>4)*8+e ; B[k][n]: n=lane&15, k=(lane>>4)*8+e
//   D[m][n]: n=lane&15, m=(lane>>4)*4+reg
// ---------------------------------------------------------------------------
__global__ __launch_bounds__(256, 2) void gemm_kernel(const float* __restrict__ feats,
                                                      const u16* __restrict__ Wh,
                                                      const u16* __restrict__ Wl,
                                                      const float* __restrict__ bias,
                                                      float* __restrict__ emission) {
    __shared__ float2 A2[4][16][33];      // per-wave private 16x64-float tile, +pad
    const int tid  = threadIdx.x;
    const int lane = tid & 63;
    const int w    = tid >> 6;            // wave 0..3
    const int r16  = lane & 15;           // A-row in tile / output col
    const int g    = lane >> 4;           // 0..3 (k-group)
    const int mtile = blockIdx.x * 4 + w;
    const long row0 = (long)mtile * 16;

    const int srow  = lane >> 4;          // staging: row sub-index 0..3
    const int sslot = lane & 15;          // staging: 16B slot within row-chunk

    const float* fb = feats + row0 * H_;
    const u16* bh0p = Wh + r16 * H_;
    const u16* bl0p = Wl + r16 * H_;
    const u16* bh1p = Wh + (r16 + 16) * H_;
    const u16* bl1p = Wl + (r16 + 16) * H_;

    f32x4 acc0 = {0.f, 0.f, 0.f, 0.f};
    f32x4 acc1 = {0.f, 0.f, 0.f, 0.f};

    float4 rgA[4], rgB[4];

#define LOADCH(rg, c)                                                          \
    do {                                                                       \
        _Pragma("unroll") for (int i = 0; i < 4; ++i)                          \
            rg[i] = *(const float4*)(fb + (long)(4 * i + srow) * H_ +          \
                                     (c) * 64 + sslot * 4);                    \
    } while (0)

#define WRITECH(rg)                                                            \
    do {                                                                       \
        _Pragma("unroll") for (int i = 0; i < 4; ++i) {                        \
            A2[w][4 * i + srow][sslot * 2]     = make_float2(rg[i].x, rg[i].y);\
            A2[w][4 * i + srow][sslot * 2 + 1] = make_float2(rg[i].z, rg[i].w);\
        }                                                                      \
    } while (0)

#define COMPCH(c)                                                              \
    do {                                                                       \
        _Pragma("unroll") for (int t = 0; t < 2; ++t) {                        \
            const float2 f0 = A2[w][r16][16 * t + 4 * g + 0];                  \
            const float2 f1 = A2[w][r16][16 * t + 4 * g + 1];                  \
            const float2 f2 = A2[w][r16][16 * t + 4 * g + 2];                  \
            const float2 f3 = A2[w][r16][16 * t + 4 * g + 3];                  \
            const int ko = (c) * 64 + t * 32 + g * 8;                          \
            const short8v bh0 = *(const short8v*)(bh0p + ko);                  \
            const short8v bl0 = *(const short8v*)(bl0p + ko);                  \
            const short8v bh1 = *(const short8v*)(bh1p + ko);                  \
            const short8v bl1 = *(const short8v*)(bl1p + ko);                  \
            u32 h0, l0, h1, l1, h2, l2, h3, l3;                                \
            split_pk(f0.x, f0.y, h0, l0);                                      \
            split_pk(f1.x, f1.y, h1, l1);                                      \
            split_pk(f2.x, f2.y, h2, l2);                                      \
            split_pk(f3.x, f3.y, h3, l3);                                      \
            const uint4v hv = {h0, h1, h2, h3};                                \
            const uint4v lv = {l0, l1, l2, l3};                                \
            const short8v ah = __builtin_bit_cast(short8v, hv);                \
            const short8v al = __builtin_bit_cast(short8v, lv);                \
            acc0 = __builtin_amdgcn_mfma_f32_16x16x32_bf16(al, bh0, acc0, 0, 0, 0); \
            acc0 = __builtin_amdgcn_mfma_f32_16x16x32_bf16(ah, bl0, acc0, 0, 0, 0); \
            acc0 = __builtin_amdgcn_mfma_f32_16x16x32_bf16(ah, bh0, acc0, 0, 0, 0); \
            acc1 = __builtin_amdgcn_mfma_f32_16x16x32_bf16(al, bh1, acc1, 0, 0, 0); \
            acc1 = __builtin_amdgcn_mfma_f32_16x16x32_bf16(ah, bl1, acc1, 0, 0, 0); \
            acc1 = __builtin_amdgcn_mfma_f32_16x16x32_bf16(ah, bh1, acc1, 0, 0, 0); \
        }                                                                      \
    } while (0)

    LOADCH(rgA, 0);
    LOADCH(rgB, 1);
#pragma unroll
    for (int c = 0; c < 16; c += 2) {
        WRITECH(rgA);                     // waits vmcnt for rgA only
        if (c + 2 < 16) LOADCH(rgA, c + 2);
        COMPCH(c);                        // ds_reads ordered after writes (in-wave)
        WRITECH(rgB);
        if (c + 3 < 16) LOADCH(rgB, c + 3);
        COMPCH(c + 1);
    }
#undef LOADCH
#undef WRITECH
#undef COMPCH

    // epilogue: C/D layout col=lane&15, row=4*(lane>>4)+reg
    const float b0 = bias[r16];
    const float b1 = (r16 + 16 < T_) ? bias[r16 + 16] : 0.f;
    float* op = emission + (row0 + g * 4) * T_;
#pragma unroll
    for (int r = 0; r < 4; ++r) {
        op[r * T_ + r16] = acc0[r] + b0;
        if (r16 + 16 < T_) op[r * T_ + r16 + 16] = acc1[r] + b1;
    }
}

// ---------------------------------------------------------------------------
// Kernel 2: parallel-scan pass 1, MFMA form — byte-identical to R3/R4/R7
// (passed three times). Chunk operator K <- diagX_s * (E^T * K), K init I(32).
// ---------------------------------------------------------------------------
__global__ __launch_bounds__(64, 1) void chunk_kernel(const float* __restrict__ emission,
                                                      const int* __restrict__ mask,
                                                      const float* __restrict__ trans,
                                                      float* __restrict__ wsK) {
    __shared__ u32 lds[2][2][16][18];   // [hl][J][rowpair][col(16)+pad]
    const int bid = blockIdx.x;
    const int c_ = bid & (NC_ - 1);     // chunk
    const int b  = bid >> 5;
    const int l  = threadIdx.x;
    const int cc = l & 15;              // col-in-tile
    const int q  = l >> 4;              // lane quarter
    const int aq4 = (l & 48);           // 4*(4q) bytes, bpermute base

    const float* em = emission + (long)b * S_ * T_;
    const int* mk = mask + b * S_;

    // len = sum(mask row) (prefix-contiguous by construction)
    int mc = 0;
#pragma unroll
    for (int k = 0; k < 8; ++k) mc += mk[l + k * 64];
#pragma unroll
    for (int off = 32; off; off >>= 1) mc += __shfl_xor(mc, off);
    const int len = __builtin_amdgcn_readfirstlane(mc);

    const int lo = 1 + c_ * CL_;
    const int hi = min(lo + CL_, S_);
    const int send = min(hi, len);      // uniform

    // A-frags: A_I[m][k] = E^T[16I+cc][8q+e] = exp(trans[(8q+e)*24 + 16I+cc])
    short8v Ah[2], Al[2];
#pragma unroll
    for (int I = 0; I < 2; ++I) {
        const int j = 16 * I + cc;
        u32 hw[4], lw[4];
#pragma unroll
        for (int w = 0; w < 4; ++w) {
            const int t0 = 8 * q + 2 * w;
            const float v0 = (t0 < 24 && j < 24) ? __expf(trans[t0 * T_ + j]) : 0.f;
            const float v1 = (t0 + 1 < 24 && j < 24) ? __expf(trans[(t0 + 1) * T_ + j]) : 0.f;
            split_pk(v0, v1, hw[w], lw[w]);
        }
        const uint4v hv = {hw[0], hw[1], hw[2], hw[3]};
        const uint4v lv = {lw[0], lw[1], lw[2], lw[3]};
        Ah[I] = __builtin_bit_cast(short8v, hv);
        Al[I] = __builtin_bit_cast(short8v, lv);
    }

    // K regs (C/D layout): K[I][J] reg r holds K[16I+4q+r][16J+cc]; init identity
    f32x4 K[2][2];
#pragma unroll
    for (int I = 0; I < 2; ++I)
#pragma unroll
        for (int J = 0; J < 2; ++J)
#pragma unroll
            for (int r = 0; r < 4; ++r)
                K[I][J][r] = (16 * I + 4 * q + r == 16 * J + cc) ? 1.f : 0.f;

    // initial B words (identity): word w covers k = 8q+2w, 8q+2w+1; col 16J+cc
    u32 bh[2][4], bl[2][4];
#pragma unroll
    for (int J = 0; J < 2; ++J)
#pragma unroll
        for (int w = 0; w < 4; ++w) {
            const int k0 = 8 * q + 2 * w, col = 16 * J + cc;
            bh[J][w] = (k0 == col ? 0x3f80u : 0u) | (k0 + 1 == col ? 0x3f800000u : 0u);
            bl[J][w] = 0u;
        }

    // preload raw emissions for X: lane holds em[s][l&31] (clamped index)
    const int xj = ((l & 31) < 24) ? (l & 31) : 0;
    float xr_[CL_];
#pragma unroll
    for (int k = 0; k < CL_; ++k) {
        const int s = lo + k;
        xr_[k] = em[((s < S_) ? s : 0) * T_ + xj];
    }

    float Ls = 0.f;
    const f32x4 z4 = {0.f, 0.f, 0.f, 0.f};

#pragma unroll
    for (int k = 0; k < CL_; ++k) {
        const int s = lo + k;
        if (s < send) {                 // uniform branch
            const uint4v bh0v = {bh[0][0], bh[0][1], bh[0][2], bh[0][3]};
            const uint4v bh1v = {bh[1][0], bh[1][1], bh[1][2], bh[1][3]};
            const uint4v bl0v = {bl[0][0], bl[0][1], bl[0][2], bl[0][3]};
            const uint4v bl1v = {bl[1][0], bl[1][1], bl[1][2], bl[1][3]};
            const short8v B0h = __builtin_bit_cast(short8v, bh0v);
            const short8v B1h = __builtin_bit_cast(short8v, bh1v);
            const short8v B0l = __builtin_bit_cast(short8v, bl0v);
            const short8v B1l = __builtin_bit_cast(short8v, bl1v);

            f32x4 acc[2][2];
#pragma unroll
            for (int I = 0; I < 2; ++I) {
                acc[I][0] = __builtin_amdgcn_mfma_f32_16x16x32_bf16(Ah[I], B0h, z4, 0, 0, 0);
                acc[I][0] = __builtin_amdgcn_mfma_f32_16x16x32_bf16(Ah[I], B0l, acc[I][0], 0, 0, 0);
                acc[I][0] = __builtin_amdgcn_mfma_f32_16x16x32_bf16(Al[I], B0h, acc[I][0], 0, 0, 0);
                acc[I][1] = __builtin_amdgcn_mfma_f32_16x16x32_bf16(Ah[I], B1h, z4, 0, 0, 0);
                acc[I][1] = __builtin_amdgcn_mfma_f32_16x16x32_bf16(Ah[I], B1l, acc[I][1], 0, 0, 0);
                acc[I][1] = __builtin_amdgcn_mfma_f32_16x16x32_bf16(Al[I], B1h, acc[I][1], 0, 0, 0);
            }

            // row scales: X[16I+4q+r] via bpermute of lane-held X[l&31]
            const float X = __expf(xr_[k]);
            const int xi = __float_as_int(X);
            float xr0[4], xr1[4];
#pragma unroll
            for (int r = 0; r < 4; ++r) {
                xr0[r] = __int_as_float(__builtin_amdgcn_ds_bpermute(aq4 + 4 * r, xi));
                xr1[r] = __int_as_float(__builtin_amdgcn_ds_bpermute(aq4 + 64 + 4 * r, xi));
            }
#pragma unroll
            for (int J = 0; J < 2; ++J)
#pragma unroll
                for (int r = 0; r < 4; ++r) {
                    K[0][J][r] = acc[0][J][r] * xr0[r];
                    K[1][J][r] = acc[1][J][r] * xr1[r];
                }

            if (k == 7 || k == CL_ - 1) {   // exact power-of-2 renorm
                float mx = K[0][0][0];
#pragma unroll
                for (int I = 0; I < 2; ++I)
#pragma unroll
                    for (int J = 0; J < 2; ++J)
#pragma unroll
                        for (int r = 0; r < 4; ++r) mx = fmaxf(mx, K[I][J][r]);
#pragma unroll
                for (int off = 32; off; off >>= 1) mx = fmaxf(mx, __shfl_xor(mx, off));
                const u32 ef = __float_as_uint(mx) & 0x7f800000u;
                const float inv = __uint_as_float(0x7f000000u - ef);
#pragma unroll
                for (int I = 0; I < 2; ++I)
#pragma unroll
                    for (int J = 0; J < 2; ++J)
#pragma unroll
                        for (int r = 0; r < 4; ++r) K[I][J][r] *= inv;
                Ls += (float)((int)(ef >> 23) - 127) * 0.6931471805599453f;
            }

            if (k < CL_ - 1) {
                // pack K to bf16 hi/lo pairs and bounce through LDS to B layout
#pragma unroll
                for (int I = 0; I < 2; ++I)
#pragma unroll
                    for (int J = 0; J < 2; ++J)
#pragma unroll
                        for (int m = 0; m < 2; ++m) {
                            u32 h, lo_w;
                            split_pk(K[I][J][2 * m], K[I][J][2 * m + 1], h, lo_w);
                            const int p = 8 * I + 2 * q + m;
                            lds[0][J][p][cc] = h;
                            lds[1][J][p][cc] = lo_w;
                        }
                // single wave per block: DS-pipe in-order + compiler lgkmcnt
#pragma unroll
                for (int J = 0; J < 2; ++J)
#pragma unroll
                    for (int w = 0; w < 4; ++w) {
                        bh[J][w] = lds[0][J][4 * q + w][cc];
                        bl[J][w] = lds[1][J][4 * q + w][cc];
                    }
            }
        }
    }

    // store K row-major [j][t] (+ Ls) for pass 2
    float* outp = wsK + (long)(b * NC_ + c_) * KST_;
#pragma unroll
    for (int I = 0; I < 2; ++I)
#pragma unroll
        for (int J = 0; J < 2; ++J)
#pragma unroll
            for (int r = 0; r < 4; ++r)
                outp[(16 * I + 4 * q + r) * 32 + 16 * J + cc] = K[I][J][r];
    if (l == 0) outp[1024] = Ls;
}

// ---------------------------------------------------------------------------
// Kernel 3: pass 2 — byte-identical to R7 (prefetch + renorm-every-2).
// ---------------------------------------------------------------------------
#define ACC4(kv, t0)                                                           \
    s0 = fmaf(rl_f32(p, (t0) + 0), kv.x, s0);                                  \
    s1 = fmaf(rl_f32(p, (t0) + 1), kv.y, s1);                                  \
    s2 = fmaf(rl_f32(p, (t0) + 2), kv.z, s2);                                  \
    s3 = fmaf(rl_f32(p, (t0) + 3), kv.w, s3);

__global__ __launch_bounds__(64) void finalize_kernel(const float* __restrict__ emission,
                                                      const int* __restrict__ target,
                                                      const int* __restrict__ mask,
                                                      const float* __restrict__ trans,
                                                      const float* __restrict__ wsK,
                                                      float* __restrict__ out) {
    const int b = blockIdx.x;
    const int j = threadIdx.x;
    const int jj = j < 24 ? j : 23;
    const float* em = emission + (long)b * S_ * T_;
    const int* mk = mask + b * S_;

    float p = (j < 24) ? __expf(em[j]) : 0.f;   // p0
    float C = 0.f;

    const float* base = wsK + (long)b * NC_ * KST_;

    // prime the prefetch registers with chunk 0
    const float4* rp0 = (const float4*)(base + jj * 32);
    float4 n0 = rp0[0], n1 = rp0[1], n2 = rp0[2], n3 = rp0[3], n4 = rp0[4], n5 = rp0[5];
    float nL = base[1024];

    for (int c = 0; c < NC_; ++c) {
        const float4 k0 = n0, k1 = n1, k2 = n2, k3 = n3, k4 = n4, k5 = n5;
        const float L = nL;
        if (c + 1 < NC_) {                      // issue next chunk's loads early
            const float* nb = base + (long)(c + 1) * KST_;
            const float4* np = (const float4*)(nb + jj * 32);
            n0 = np[0]; n1 = np[1]; n2 = np[2]; n3 = np[3]; n4 = np[4]; n5 = np[5];
            nL = nb[1024];
        }
        C += L;                                 // chunk log-scale (uniform)
        float s0 = 0.f, s1 = 0.f, s2 = 0.f, s3 = 0.f;
        ACC4(k0, 0) ACC4(k1, 4) ACC4(k2, 8) ACC4(k3, 12) ACC4(k4, 16) ACC4(k5, 20)
        p = (j < 24) ? ((s0 + s1) + (s2 + s3)) : 0.f;
        if ((c & 1) || c == NC_ - 1) {          // exact power-of-2 renorm, every 2
            float mx = p;
#pragma unroll
            for (int off = 32; off; off >>= 1) mx = fmaxf(mx, __shfl_xor(mx, off));
            const u32 ef = __float_as_uint(mx) & 0x7f800000u;
            p *= __uint_as_float(0x7f000000u - ef);
            C += (float)((int)(ef >> 23) - 127) * 0.6931471805599453f;
        }
    }

    float ex = p;                               // lanes>=24 already 0
#pragma unroll
    for (int off = 32; off; off >>= 1) ex += __shfl_down(ex, off);

    // gold-path score (all 64 lanes)
    float ssum = 0.f;
#pragma unroll
    for (int kk = 0; kk < S_ / 64; ++kk) {
        const int s = j + kk * 64;
        if (mk[s]) {
            const int tg = target[b * S_ + s];
            float v = em[s * T_ + tg];
            if (s > 0) v += trans[target[b * S_ + s - 1] * T_ + tg];
            ssum += v;
        }
    }
#pragma unroll
    for (int off = 32; off; off >>= 1) ssum += __shfl_down(ssum, off);

    if (j == 0) {
        const float logZ = C + __logf(ex);
        atomicAdd(out, (logZ - ssum) * (1.0f / B_));
    }
}

extern "C" void kernel_launch(void* const* d_in, const int* in_sizes, int n_in,
                              void* d_out, int out_size, void* d_ws, size_t ws_size,
                              hipStream_t stream) {
    const float* feats  = (const float*)d_in[0];
    const int*   target = (const int*)d_in[1];
    const int*   mask   = (const int*)d_in[2];
    const float* W      = (const float*)d_in[3];
    const float* bias   = (const float*)d_in[4];
    const float* trans  = (const float*)d_in[5];

    float* out = (float*)d_out;
    float* emission = out + 1;            // output 1, written in place
    u16* Wh = (u16*)d_ws;                 // 32*1024 bf16 = 64 KB
    u16* Wl = Wh + TP_ * H_;              // 64 KB
    float* wsK = (float*)((char*)d_ws + 131072);      // 2048 * 1040 floats ~ 8.5 MB

    wcvt_kernel<<<(TP_ * H_) / 256, 256, 0, stream>>>(W, Wh, Wl, out);
    gemm_kernel<<<512, 256, 0, stream>>>(feats, Wh, Wl, bias, emission);
    chunk_kernel<<<B_ * NC_, 64, 0, stream>>>(emission, mask, trans, wsK);
    finalize_kernel<<<B_, 64, 0, stream>>>(emission, target, mask, trans, wsK, out);
}

// Round 9
// 251.921 us; speedup vs baseline: 1.0522x; 1.0522x over previous
//
#include <hip/hip_runtime.h>
#include <cstdint>
#include <math.h>

#define B_ 64
#define S_ 512
#define H_ 1024
#define T_ 24
#define TP_ 32     // W padded to 32 rows (zeros) so B-fragment loads never go OOB
#define NC_ 32     // chunks per batch (parallel-scan)
#define CL_ 16     // chunk length in steps
#define KST_ 1040  // floats per (batch,chunk) record: 32x32 K row-major + Ls + pad

typedef unsigned int u32;
typedef unsigned short u16;
typedef __attribute__((ext_vector_type(8))) short short8v;  // 8 bf16 = 4 VGPRs
typedef __attribute__((ext_vector_type(4))) float f32x4;
typedef __attribute__((ext_vector_type(4))) u32 uint4v;

// readlane: value from lane `sl` (wave-uniform index ok), bitcast through uint
__device__ __forceinline__ float rl_f32(float x, int sl) {
    return __uint_as_float(__builtin_amdgcn_readlane(__float_as_uint(x), sl));
}

// Exact-ish two-term split: f = hi + lo (both bf16 by truncation).
// Packs two elements' hi (lo) into one u32, low element in low half.
__device__ __forceinline__ void split_pk(float f0, float f1, u32& hpk, u32& lpk) {
    const u32 u0 = __float_as_uint(f0), u1 = __float_as_uint(f1);
    const u32 t1 = u1 & 0xffff0000u;
    hpk = (u0 >> 16) | t1;
    const float fl0 = f0 - __uint_as_float(u0 & 0xffff0000u);
    const float fl1 = f1 - __uint_as_float(t1);
    lpk = (__float_as_uint(fl0) >> 16) | (__float_as_uint(fl1) & 0xffff0000u);
}

// ---------------------------------------------------------------------------
// Kernel 0: one-shot W split fp32 -> bf16 hi/lo (RTNE), padded to 32 rows.
// Also zeroes the loss accumulator out[0] (re-zeroed every graph replay).
// (R9: byte-level revert to the R7 build — best verified at 254.6 µs.
//  Experiment history: R4 K-split neutral, R5 mega-fusion −84 µs, R6
//  per-block device-fence −92 µs, R7 finalize prefetch +4.5 µs, R8
//  LDS-staged gemm −10 µs. The R4-form gemm is the effective floor.)
// ---------------------------------------------------------------------------
__global__ __launch_bounds__(256) void wcvt_kernel(const float* __restrict__ W,
                                                   u16* __restrict__ Wh,
                                                   u16* __restrict__ Wl,
                                                   float* __restrict__ out) {
    const int i = blockIdx.x * 256 + threadIdx.x;       // 0 .. 32*1024-1
    if (i == 0) out[0] = 0.f;
    const int t = i >> 10;
    const float f = (t < T_) ? W[i] : 0.f;              // W is [24][1024]; i = t*1024+k
    const u32 u = __float_as_uint(f);
    const u32 rh = u + 0x7fffu + ((u >> 16) & 1u);      // RTNE
    const u16 hb = (u16)(rh >> 16);
    const float fh = __uint_as_float((u32)hb << 16);
    const float fl = f - fh;
    const u32 u2 = __float_as_uint(fl);
    const u32 rl2 = u2 + 0x7fffu + ((u2 >> 16) & 1u);
    Wh[i] = hb;
    Wl[i] = (u16)(rl2 >> 16);
}

// ---------------------------------------------------------------------------
// Kernel 1: emission GEMM via MFMA (bf16 hi/lo split) — byte-identical to R4
// (the best verified configuration). 2-way K-split; 1024 blocks x 4 waves.
// Verified conventions for mfma_f32_16x16x32_bf16 (by this kernel passing):
//   A[m][k]: m=lane&15, k=(lane>>4)*8+e ; B[k][n]: n=lane&15, k=(lane>>4)*8+e
//   D[m][n]: n=lane&15, m=(lane>>4)*4+reg
// ---------------------------------------------------------------------------
__global__ __launch_bounds__(256, 4) void gemm_kernel(const float* __restrict__ feats,
                                                      const u16* __restrict__ Wh,
                                                      const u16* __restrict__ Wl,
                                                      const float* __restrict__ bias,
                                                      float* __restrict__ emission) {
    __shared__ f32x4 ldsP[2][64][2];      // partner partials [mtile-in-block][lane][acc0/1]
    const int tid  = threadIdx.x;
    const int lane = tid & 63;
    const int wv   = tid >> 6;            // wave 0..3
    const int mt_in = wv & 1;             // which M-tile of this block
    const int kh    = wv >> 1;            // K-half 0/1
    const int r16  = lane & 15;           // A-row in tile / output col
    const int g    = lane >> 4;           // 0..3 (k-group)
    const int mtile = blockIdx.x * 2 + mt_in;

    const long ko0 = (long)kh * 512 + g * 8;
    const float* ap  = feats + ((long)mtile * 16 + r16) * H_ + ko0;
    const u16* bh0p = Wh + r16 * H_ + ko0;           // Nfrag0: cols 0..15
    const u16* bl0p = Wl + r16 * H_ + ko0;
    const u16* bh1p = Wh + (r16 + 16) * H_ + ko0;    // Nfrag1: cols 16..31 (zero-padded)
    const u16* bl1p = Wl + (r16 + 16) * H_ + ko0;

    f32x4 acc0 = {0.f, 0.f, 0.f, 0.f};
    f32x4 acc1 = {0.f, 0.f, 0.f, 0.f};

    // 3-stage software pipeline (all indices compile-time under full unroll)
    float4 A0[3], A1[3];
    short8v BH0[3], BL0[3], BH1[3], BL1[3];
#pragma unroll
    for (int p = 0; p < 3; ++p) {
        const int ko = p * 32;
        A0[p]  = *(const float4*)(ap + ko);
        A1[p]  = *(const float4*)(ap + ko + 4);
        BH0[p] = *(const short8v*)(bh0p + ko);
        BL0[p] = *(const short8v*)(bl0p + ko);
        BH1[p] = *(const short8v*)(bh1p + ko);
        BL1[p] = *(const short8v*)(bl1p + ko);
    }

#pragma unroll
    for (int kk = 0; kk < 16; ++kk) {
        const int sl = kk % 3;
        const float4 a0 = A0[sl];
        const float4 a1 = A1[sl];
        const short8v bh0 = BH0[sl];
        const short8v bl0 = BL0[sl];
        const short8v bh1 = BH1[sl];
        const short8v bl1 = BL1[sl];
        if (kk + 3 < 16) {                 // refill freed slot, 3 iters ahead
            const int ko = (kk + 3) * 32;
            A0[sl]  = *(const float4*)(ap + ko);
            A1[sl]  = *(const float4*)(ap + ko + 4);
            BH0[sl] = *(const short8v*)(bh0p + ko);
            BL0[sl] = *(const short8v*)(bl0p + ko);
            BH1[sl] = *(const short8v*)(bh1p + ko);
            BL1[sl] = *(const short8v*)(bl1p + ko);
        }

        u32 h0, l0, h1, l1, h2, l2, h3, l3;
        split_pk(a0.x, a0.y, h0, l0);
        split_pk(a0.z, a0.w, h1, l1);
        split_pk(a1.x, a1.y, h2, l2);
        split_pk(a1.z, a1.w, h3, l3);
        const uint4v hv = {h0, h1, h2, h3};
        const uint4v lv = {l0, l1, l2, l3};
        const short8v ah = __builtin_bit_cast(short8v, hv);
        const short8v al = __builtin_bit_cast(short8v, lv);

        acc0 = __builtin_amdgcn_mfma_f32_16x16x32_bf16(al, bh0, acc0, 0, 0, 0);
        acc0 = __builtin_amdgcn_mfma_f32_16x16x32_bf16(ah, bl0, acc0, 0, 0, 0);
        acc0 = __builtin_amdgcn_mfma_f32_16x16x32_bf16(ah, bh0, acc0, 0, 0, 0);
        acc1 = __builtin_amdgcn_mfma_f32_16x16x32_bf16(al, bh1, acc1, 0, 0, 0);
        acc1 = __builtin_amdgcn_mfma_f32_16x16x32_bf16(ah, bl1, acc1, 0, 0, 0);
        acc1 = __builtin_amdgcn_mfma_f32_16x16x32_bf16(ah, bh1, acc1, 0, 0, 0);
    }

    // combine K-halves: kh=1 waves publish, kh=0 waves reduce + write out
    if (kh == 1) {
        ldsP[mt_in][lane][0] = acc0;
        ldsP[mt_in][lane][1] = acc1;
    }
    __syncthreads();
    if (kh == 0) {
        const f32x4 p0 = ldsP[mt_in][lane][0];
        const f32x4 p1 = ldsP[mt_in][lane][1];
#pragma unroll
        for (int r = 0; r < 4; ++r) {
            acc0[r] += p0[r];
            acc1[r] += p1[r];
        }
        // epilogue: C/D layout col=lane&15, row=4*(lane>>4)+reg
        const float b0 = bias[r16];
        const float b1 = (r16 + 16 < T_) ? bias[r16 + 16] : 0.f;
        float* op = emission + ((long)mtile * 16 + g * 4) * T_;
#pragma unroll
        for (int r = 0; r < 4; ++r) {
            op[r * T_ + r16] = acc0[r] + b0;
            if (r16 + 16 < T_) op[r * T_ + r16 + 16] = acc1[r] + b1;
        }
    }
}

// ---------------------------------------------------------------------------
// Kernel 2: parallel-scan pass 1, MFMA form — byte-identical to R3/R4/R7
// (passed three times). Chunk operator K <- diagX_s * (E^T * K), K init I(32).
// ---------------------------------------------------------------------------
__global__ __launch_bounds__(64, 1) void chunk_kernel(const float* __restrict__ emission,
                                                      const int* __restrict__ mask,
                                                      const float* __restrict__ trans,
                                                      float* __restrict__ wsK) {
    __shared__ u32 lds[2][2][16][18];   // [hl][J][rowpair][col(16)+pad]
    const int bid = blockIdx.x;
    const int c_ = bid & (NC_ - 1);     // chunk
    const int b  = bid >> 5;
    const int l  = threadIdx.x;
    const int cc = l & 15;              // col-in-tile
    const int q  = l >> 4;              // lane quarter
    const int aq4 = (l & 48);           // 4*(4q) bytes, bpermute base

    const float* em = emission + (long)b * S_ * T_;
    const int* mk = mask + b * S_;

    // len = sum(mask row) (prefix-contiguous by construction)
    int mc = 0;
#pragma unroll
    for (int k = 0; k < 8; ++k) mc += mk[l + k * 64];
#pragma unroll
    for (int off = 32; off; off >>= 1) mc += __shfl_xor(mc, off);
    const int len = __builtin_amdgcn_readfirstlane(mc);

    const int lo = 1 + c_ * CL_;
    const int hi = min(lo + CL_, S_);
    const int send = min(hi, len);      // uniform

    // A-frags: A_I[m][k] = E^T[16I+cc][8q+e] = exp(trans[(8q+e)*24 + 16I+cc])
    short8v Ah[2], Al[2];
#pragma unroll
    for (int I = 0; I < 2; ++I) {
        const int j = 16 * I + cc;
        u32 hw[4], lw[4];
#pragma unroll
        for (int w = 0; w < 4; ++w) {
            const int t0 = 8 * q + 2 * w;
            const float v0 = (t0 < 24 && j < 24) ? __expf(trans[t0 * T_ + j]) : 0.f;
            const float v1 = (t0 + 1 < 24 && j < 24) ? __expf(trans[(t0 + 1) * T_ + j]) : 0.f;
            split_pk(v0, v1, hw[w], lw[w]);
        }
        const uint4v hv = {hw[0], hw[1], hw[2], hw[3]};
        const uint4v lv = {lw[0], lw[1], lw[2], lw[3]};
        Ah[I] = __builtin_bit_cast(short8v, hv);
        Al[I] = __builtin_bit_cast(short8v, lv);
    }

    // K regs (C/D layout): K[I][J] reg r holds K[16I+4q+r][16J+cc]; init identity
    f32x4 K[2][2];
#pragma unroll
    for (int I = 0; I < 2; ++I)
#pragma unroll
        for (int J = 0; J < 2; ++J)
#pragma unroll
            for (int r = 0; r < 4; ++r)
                K[I][J][r] = (16 * I + 4 * q + r == 16 * J + cc) ? 1.f : 0.f;

    // initial B words (identity): word w covers k = 8q+2w, 8q+2w+1; col 16J+cc
    u32 bh[2][4], bl[2][4];
#pragma unroll
    for (int J = 0; J < 2; ++J)
#pragma unroll
        for (int w = 0; w < 4; ++w) {
            const int k0 = 8 * q + 2 * w, col = 16 * J + cc;
            bh[J][w] = (k0 == col ? 0x3f80u : 0u) | (k0 + 1 == col ? 0x3f800000u : 0u);
            bl[J][w] = 0u;
        }

    // preload raw emissions for X: lane holds em[s][l&31] (clamped index)
    const int xj = ((l & 31) < 24) ? (l & 31) : 0;
    float xr_[CL_];
#pragma unroll
    for (int k = 0; k < CL_; ++k) {
        const int s = lo + k;
        xr_[k] = em[((s < S_) ? s : 0) * T_ + xj];
    }

    float Ls = 0.f;
    const f32x4 z4 = {0.f, 0.f, 0.f, 0.f};

#pragma unroll
    for (int k = 0; k < CL_; ++k) {
        const int s = lo + k;
        if (s < send) {                 // uniform branch
            const uint4v bh0v = {bh[0][0], bh[0][1], bh[0][2], bh[0][3]};
            const uint4v bh1v = {bh[1][0], bh[1][1], bh[1][2], bh[1][3]};
            const uint4v bl0v = {bl[0][0], bl[0][1], bl[0][2], bl[0][3]};
            const uint4v bl1v = {bl[1][0], bl[1][1], bl[1][2], bl[1][3]};
            const short8v B0h = __builtin_bit_cast(short8v, bh0v);
            const short8v B1h = __builtin_bit_cast(short8v, bh1v);
            const short8v B0l = __builtin_bit_cast(short8v, bl0v);
            const short8v B1l = __builtin_bit_cast(short8v, bl1v);

            f32x4 acc[2][2];
#pragma unroll
            for (int I = 0; I < 2; ++I) {
                acc[I][0] = __builtin_amdgcn_mfma_f32_16x16x32_bf16(Ah[I], B0h, z4, 0, 0, 0);
                acc[I][0] = __builtin_amdgcn_mfma_f32_16x16x32_bf16(Ah[I], B0l, acc[I][0], 0, 0, 0);
                acc[I][0] = __builtin_amdgcn_mfma_f32_16x16x32_bf16(Al[I], B0h, acc[I][0], 0, 0, 0);
                acc[I][1] = __builtin_amdgcn_mfma_f32_16x16x32_bf16(Ah[I], B1h, z4, 0, 0, 0);
                acc[I][1] = __builtin_amdgcn_mfma_f32_16x16x32_bf16(Ah[I], B1l, acc[I][1], 0, 0, 0);
                acc[I][1] = __builtin_amdgcn_mfma_f32_16x16x32_bf16(Al[I], B1h, acc[I][1], 0, 0, 0);
            }

            // row scales: X[16I+4q+r] via bpermute of lane-held X[l&31]
            const float X = __expf(xr_[k]);
            const int xi = __float_as_int(X);
            float xr0[4], xr1[4];
#pragma unroll
            for (int r = 0; r < 4; ++r) {
                xr0[r] = __int_as_float(__builtin_amdgcn_ds_bpermute(aq4 + 4 * r, xi));
                xr1[r] = __int_as_float(__builtin_amdgcn_ds_bpermute(aq4 + 64 + 4 * r, xi));
            }
#pragma unroll
            for (int J = 0; J < 2; ++J)
#pragma unroll
                for (int r = 0; r < 4; ++r) {
                    K[0][J][r] = acc[0][J][r] * xr0[r];
                    K[1][J][r] = acc[1][J][r] * xr1[r];
                }

            if (k == 7 || k == CL_ - 1) {   // exact power-of-2 renorm
                float mx = K[0][0][0];
#pragma unroll
                for (int I = 0; I < 2; ++I)
#pragma unroll
                    for (int J = 0; J < 2; ++J)
#pragma unroll
                        for (int r = 0; r < 4; ++r) mx = fmaxf(mx, K[I][J][r]);
#pragma unroll
                for (int off = 32; off; off >>= 1) mx = fmaxf(mx, __shfl_xor(mx, off));
                const u32 ef = __float_as_uint(mx) & 0x7f800000u;
                const float inv = __uint_as_float(0x7f000000u - ef);
#pragma unroll
                for (int I = 0; I < 2; ++I)
#pragma unroll
                    for (int J = 0; J < 2; ++J)
#pragma unroll
                        for (int r = 0; r < 4; ++r) K[I][J][r] *= inv;
                Ls += (float)((int)(ef >> 23) - 127) * 0.6931471805599453f;
            }

            if (k < CL_ - 1) {
                // pack K to bf16 hi/lo pairs and bounce through LDS to B layout
#pragma unroll
                for (int I = 0; I < 2; ++I)
#pragma unroll
                    for (int J = 0; J < 2; ++J)
#pragma unroll
                        for (int m = 0; m < 2; ++m) {
                            u32 h, lo_w;
                            split_pk(K[I][J][2 * m], K[I][J][2 * m + 1], h, lo_w);
                            const int p = 8 * I + 2 * q + m;
                            lds[0][J][p][cc] = h;
                            lds[1][J][p][cc] = lo_w;
                        }
                // single wave per block: DS-pipe in-order + compiler lgkmcnt
#pragma unroll
                for (int J = 0; J < 2; ++J)
#pragma unroll
                    for (int w = 0; w < 4; ++w) {
                        bh[J][w] = lds[0][J][4 * q + w][cc];
                        bl[J][w] = lds[1][J][4 * q + w][cc];
                    }
            }
        }
    }

    // store K row-major [j][t] (+ Ls) for pass 2
    float* outp = wsK + (long)(b * NC_ + c_) * KST_;
#pragma unroll
    for (int I = 0; I < 2; ++I)
#pragma unroll
        for (int J = 0; J < 2; ++J)
#pragma unroll
            for (int r = 0; r < 4; ++r)
                outp[(16 * I + 4 * q + r) * 32 + 16 * J + cc] = K[I][J][r];
    if (l == 0) outp[1024] = Ls;
}

// ---------------------------------------------------------------------------
// Kernel 3: pass 2 — byte-identical to R7 (prefetch + renorm-every-2).
// ---------------------------------------------------------------------------
#define ACC4(kv, t0)                                                           \
    s0 = fmaf(rl_f32(p, (t0) + 0), kv.x, s0);                                  \
    s1 = fmaf(rl_f32(p, (t0) + 1), kv.y, s1);                                  \
    s2 = fmaf(rl_f32(p, (t0) + 2), kv.z, s2);                                  \
    s3 = fmaf(rl_f32(p, (t0) + 3), kv.w, s3);

__global__ __launch_bounds__(64) void finalize_kernel(const float* __restrict__ emission,
                                                      const int* __restrict__ target,
                                                      const int* __restrict__ mask,
                                                      const float* __restrict__ trans,
                                                      const float* __restrict__ wsK,
                                                      float* __restrict__ out) {
    const int b = blockIdx.x;
    const int j = threadIdx.x;
    const int jj = j < 24 ? j : 23;
    const float* em = emission + (long)b * S_ * T_;
    const int* mk = mask + b * S_;

    float p = (j < 24) ? __expf(em[j]) : 0.f;   // p0
    float C = 0.f;

    const float* base = wsK + (long)b * NC_ * KST_;

    // prime the prefetch registers with chunk 0
    const float4* rp0 = (const float4*)(base + jj * 32);
    float4 n0 = rp0[0], n1 = rp0[1], n2 = rp0[2], n3 = rp0[3], n4 = rp0[4], n5 = rp0[5];
    float nL = base[1024];

    for (int c = 0; c < NC_; ++c) {
        const float4 k0 = n0, k1 = n1, k2 = n2, k3 = n3, k4 = n4, k5 = n5;
        const float L = nL;
        if (c + 1 < NC_) {                      // issue next chunk's loads early
            const float* nb = base + (long)(c + 1) * KST_;
            const float4* np = (const float4*)(nb + jj * 32);
            n0 = np[0]; n1 = np[1]; n2 = np[2]; n3 = np[3]; n4 = np[4]; n5 = np[5];
            nL = nb[1024];
        }
        C += L;                                 // chunk log-scale (uniform)
        float s0 = 0.f, s1 = 0.f, s2 = 0.f, s3 = 0.f;
        ACC4(k0, 0) ACC4(k1, 4) ACC4(k2, 8) ACC4(k3, 12) ACC4(k4, 16) ACC4(k5, 20)
        p = (j < 24) ? ((s0 + s1) + (s2 + s3)) : 0.f;
        if ((c & 1) || c == NC_ - 1) {          // exact power-of-2 renorm, every 2
            float mx = p;
#pragma unroll
            for (int off = 32; off; off >>= 1) mx = fmaxf(mx, __shfl_xor(mx, off));
            const u32 ef = __float_as_uint(mx) & 0x7f800000u;
            p *= __uint_as_float(0x7f000000u - ef);
            C += (float)((int)(ef >> 23) - 127) * 0.6931471805599453f;
        }
    }

    float ex = p;                               // lanes>=24 already 0
#pragma unroll
    for (int off = 32; off; off >>= 1) ex += __shfl_down(ex, off);

    // gold-path score (all 64 lanes)
    float ssum = 0.f;
#pragma unroll
    for (int kk = 0; kk < S_ / 64; ++kk) {
        const int s = j + kk * 64;
        if (mk[s]) {
            const int tg = target[b * S_ + s];
            float v = em[s * T_ + tg];
            if (s > 0) v += trans[target[b * S_ + s - 1] * T_ + tg];
            ssum += v;
        }
    }
#pragma unroll
    for (int off = 32; off; off >>= 1) ssum += __shfl_down(ssum, off);

    if (j == 0) {
        const float logZ = C + __logf(ex);
        atomicAdd(out, (logZ - ssum) * (1.0f / B_));
    }
}

extern "C" void kernel_launch(void* const* d_in, const int* in_sizes, int n_in,
                              void* d_out, int out_size, void* d_ws, size_t ws_size,
                              hipStream_t stream) {
    const float* feats  = (const float*)d_in[0];
    const int*   target = (const int*)d_in[1];
    const int*   mask   = (const int*)d_in[2];
    const float* W      = (const float*)d_in[3];
    const float* bias   = (const float*)d_in[4];
    const float* trans  = (const float*)d_in[5];

    float* out = (float*)d_out;
    float* emission = out + 1;            // output 1, written in place
    u16* Wh = (u16*)d_ws;                 // 32*1024 bf16 = 64 KB
    u16* Wl = Wh + TP_ * H_;              // 64 KB
    float* wsK = (float*)((char*)d_ws + 131072);      // 2048 * 1040 floats ~ 8.5 MB

    wcvt_kernel<<<(TP_ * H_) / 256, 256, 0, stream>>>(W, Wh, Wl, out);
    gemm_kernel<<<1024, 256, 0, stream>>>(feats, Wh, Wl, bias, emission);
    chunk_kernel<<<B_ * NC_, 64, 0, stream>>>(emission, mask, trans, wsK);
    finalize_kernel<<<B_, 64, 0, stream>>>(emission, target, mask, trans, wsK, out);
}